// Round 12
// baseline (34.228 us; speedup 1.0000x reference)
//
#include <hip/hip_runtime.h>
#include <stdint.h>

#define Bn 512
#define Tn 512
#define Ln 48
#define Cn 128
#define BLANKC 127
#define EPSf 1e-7f
#define LN2f 0.6931471805599453f

// DPP with 0-fill for out-of-range source lanes (bound_ctrl=1)
template<int CTRL>
__device__ __forceinline__ float dpp_f0(float x) {
    int r = __builtin_amdgcn_update_dpp(0, __float_as_int(x), CTRL, 0xF, 0xF, true);
    return __int_as_float(r);
}
// DPP keep-self for out-of-range lanes (old=self, bound_ctrl=0)
template<int CTRL>
__device__ __forceinline__ int dpp_i_keep(int x) {
    return __builtin_amdgcn_update_dpp(x, x, CTRL, 0xF, 0xF, false);
}
// ctrl: 0x138 wave_shr:1 (lane i <- i-1) ; 0x130 wave_shl:1 (lane i <- i+1)
//       0x111/0x112/0x114/0x118 row_shr:1/2/4/8 (within 16-lane row)

__global__ void __launch_bounds__(128, 1) ctc_fwd(
        const int* __restrict__ yt,
        const float* __restrict__ yp,
        float* __restrict__ out)
{
    const int b = blockIdx.x;
    const int w = threadIdx.x >> 6;   // 0 = forward wave, 1 = backward wave
    const int l = threadIdx.x & 63;

    __shared__ float ring[2][4096];   // per-wave ring: 4 slots x 16 rows x 64 lanes
    __shared__ float xb0[64], xb1[64];
    __shared__ int   xEb[64];
    __shared__ int   rmax[4];
    __shared__ float rsum[4];

    const bool lab_ok = (l < Ln);
    int  cls1 = BLANKC;
    bool allow2 = false;
    if (lab_ok) {
        cls1 = yt[b * Ln + l];
        if (l >= 1) allow2 = (cls1 != yt[b * Ln + l - 1]);
    }
    const float* gsrc0 = yp + (size_t)b * (Tn * Cn) + cls1;  // per-lane column

    float a0, a1;
    int   E = 0;
    float* lds = &ring[w][0];

#define GLDS(GP, LIDX)                                                       \
    __builtin_amdgcn_global_load_lds(                                        \
        (const __attribute__((address_space(1))) uint32_t*)(GP),             \
        (__attribute__((address_space(3))) uint32_t*)&lds[LIDX], 4, 0, 0);

#define WAIT16() asm volatile("s_waitcnt vmcnt(16)" ::: "memory");
#define WAIT0()  asm volatile("s_waitcnt vmcnt(0)"  ::: "memory");

#define RENORM()                                                     \
    {                                                                \
        float m_ = fmaxf(a0, a1);                                    \
        int   e_ = ((__float_as_int(m_) >> 23) & 0xFF) - 126;        \
        float sc_ = __int_as_float((127 - e_) << 23);                \
        a0 *= sc_; a1 *= sc_;                                        \
        E += e_;                                                     \
    }

    if (w == 0) {
        // ============ FORWARD: alpha_0 -> alpha_255 (255 steps) ===========
        // DMA chunks 0,1,2 (rows 0..47)
#pragma unroll
        for (int r = 0; r < 16; ++r) GLDS(gsrc0 + r * Cn,            (r << 6))
#pragma unroll
        for (int r = 0; r < 16; ++r) GLDS(gsrc0 + (16 + r) * Cn, (1 << 10) + (r << 6))
#pragma unroll
        for (int r = 0; r < 16; ++r) GLDS(gsrc0 + (32 + r) * Cn, (2 << 10) + (r << 6))
        WAIT16()   // chunks 0,1 resident

        a0 = (l == 0) ? lds[63] + EPSf : 0.0f;   // row 0
        a1 = (l == 0) ? lds[l]  + EPSf : 0.0f;

        // prime reg slots with rows 1..4 (slot = t&3)
        float pb1 = lds[(1 << 6) + 63], pl1 = lds[(1 << 6) + l];
        float pb2 = lds[(2 << 6) + 63], pl2 = lds[(2 << 6) + l];
        float pb3 = lds[(3 << 6) + 63], pl3 = lds[(3 << 6) + l];
        float pb0 = lds[(4 << 6) + 63], pl0 = lds[(4 << 6) + l];

        // R7-validated mul-based scale alignment (no ldexpf: OCML call suspected
        // on the critical chain; bit-constructed 2^-k multiply is 2 VALU ops,
        // k clamped to 127 -> scale=+0.0 -> exact truncation of negligible terms)
#define FSTEP(PB, PL, LID, dopf)                                     \
    {                                                                \
        float nb_ = 0.0f, nl_ = 0.0f;                                \
        if (dopf) { nb_ = lds[(LID) + 63];                           \
                    nl_ = lds[(LID) + l]; }                          \
        float p0 = (PB) + EPSf;                                      \
        float p1 = lab_ok ? (PL) + EPSf : 0.0f;                      \
        float h1 = dpp_f0<0x138>(a1);                                \
        int   Eh = dpp_i_keep<0x138>(E);                             \
        int   dm = max(E, Eh);                                       \
        int   k0 = min(dm - E, 127);                                 \
        int   kh = min(dm - Eh, 127);                                \
        float s0 = __int_as_float((127 - k0) << 23);                 \
        float sh = __int_as_float((127 - kh) << 23);                 \
        float a0c = a0 * s0, a1c = a1 * s0, h1c = h1 * sh;           \
        E = dm;                                                      \
        float t0 = a0c + h1c;                                        \
        float u  = a1c + (allow2 ? t0 : a0c);                        \
        a0 = t0 * p0;                                                \
        a1 = u * p1;                                                 \
        if (dopf) { (PB) = nb_; (PL) = nl_; }                        \
    }

        // chunk 0: t = 1..15 ; prefetch rows 5..19
        FSTEP(pb1, pl1, (5 << 6), true)
        FSTEP(pb2, pl2, (6 << 6), true)
        FSTEP(pb3, pl3, (7 << 6), true)
        RENORM()
        FSTEP(pb0, pl0, (8 << 6), true)
        FSTEP(pb1, pl1, (9 << 6), true)
        FSTEP(pb2, pl2, (10 << 6), true)
        FSTEP(pb3, pl3, (11 << 6), true)
        RENORM()
        FSTEP(pb0, pl0, (12 << 6), true)
        FSTEP(pb1, pl1, (13 << 6), true)
        FSTEP(pb2, pl2, (14 << 6), true)
        FSTEP(pb3, pl3, (15 << 6), true)
        RENORM()
        FSTEP(pb0, pl0, (1 << 10) + (0 << 6), true)   // t=12 -> r16
        FSTEP(pb1, pl1, (1 << 10) + (1 << 6), true)   // t=13 -> r17
        FSTEP(pb2, pl2, (1 << 10) + (2 << 6), true)   // t=14 -> r18
        FSTEP(pb3, pl3, (1 << 10) + (3 << 6), true)   // t=15 -> r19  [R10 bug: was missing]
        RENORM()
        // boundary 0: issue chunk 3, counted wait
#pragma unroll
        for (int r = 0; r < 16; ++r) GLDS(gsrc0 + (48 + r) * Cn, (3 << 10) + (r << 6))
        WAIT16()

#define F16(IB, INX)                                                 \
        FSTEP(pb0, pl0, (IB) + (4 << 6), true)                       \
        FSTEP(pb1, pl1, (IB) + (5 << 6), true)                       \
        FSTEP(pb2, pl2, (IB) + (6 << 6), true)                       \
        FSTEP(pb3, pl3, (IB) + (7 << 6), true)                       \
        RENORM()                                                     \
        FSTEP(pb0, pl0, (IB) + (8 << 6), true)                       \
        FSTEP(pb1, pl1, (IB) + (9 << 6), true)                       \
        FSTEP(pb2, pl2, (IB) + (10 << 6), true)                      \
        FSTEP(pb3, pl3, (IB) + (11 << 6), true)                      \
        RENORM()                                                     \
        FSTEP(pb0, pl0, (IB) + (12 << 6), true)                      \
        FSTEP(pb1, pl1, (IB) + (13 << 6), true)                      \
        FSTEP(pb2, pl2, (IB) + (14 << 6), true)                      \
        FSTEP(pb3, pl3, (IB) + (15 << 6), true)                      \
        RENORM()                                                     \
        FSTEP(pb0, pl0, (INX) + (0 << 6), true)                      \
        FSTEP(pb1, pl1, (INX) + (1 << 6), true)                      \
        FSTEP(pb2, pl2, (INX) + (2 << 6), true)                      \
        FSTEP(pb3, pl3, (INX) + (3 << 6), true)                      \
        RENORM()

        // chunks 1..12: consume 16 steps, issue chunk c+3, wait16
        for (int c = 1; c <= 12; ++c) {
            const int ib  = (c & 3) << 10;
            const int inx = ((c + 1) & 3) << 10;
            F16(ib, inx)
            const float* gc_ = gsrc0 + (size_t)((c + 3) * 16) * Cn;
            const int ibd_ = ((c + 3) & 3) << 10;
#pragma unroll
            for (int r = 0; r < 16; ++r) GLDS(gc_ + r * Cn, ibd_ + (r << 6))
            WAIT16()
        }
        // chunk 13: consume, then drain all remaining DMA
        F16((13 & 3) << 10, (14 & 3) << 10)
        WAIT0()
        // chunk 14
        F16((14 & 3) << 10, (15 & 3) << 10)
        // chunk 15: t = 240..255
        {
            const int ib = (15 & 3) << 10;
            FSTEP(pb0, pl0, ib + (4 << 6), true)
            FSTEP(pb1, pl1, ib + (5 << 6), true)
            FSTEP(pb2, pl2, ib + (6 << 6), true)
            FSTEP(pb3, pl3, ib + (7 << 6), true)
            RENORM()
            FSTEP(pb0, pl0, ib + (8 << 6), true)
            FSTEP(pb1, pl1, ib + (9 << 6), true)
            FSTEP(pb2, pl2, ib + (10 << 6), true)
            FSTEP(pb3, pl3, ib + (11 << 6), true)
            RENORM()
            FSTEP(pb0, pl0, ib + (12 << 6), true)
            FSTEP(pb1, pl1, ib + (13 << 6), true)
            FSTEP(pb2, pl2, ib + (14 << 6), true)
            FSTEP(pb3, pl3, ib + (15 << 6), true)
            RENORM()
            FSTEP(pb0, pl0, 0, false)
            FSTEP(pb1, pl1, 0, false)
            FSTEP(pb2, pl2, 0, false)
            FSTEP(pb3, pl3, 0, false)
            RENORM()
        }
#undef FSTEP
#undef F16
    } else {
        // ============ BACKWARD: beta_511 -> beta_255 (256 steps) ==========
        // chunk c row r holds global row 511-16c-r
#pragma unroll
        for (int r = 0; r < 16; ++r) GLDS(gsrc0 + (size_t)(511 - r) * Cn,            (r << 6))
#pragma unroll
        for (int r = 0; r < 16; ++r) GLDS(gsrc0 + (size_t)(495 - r) * Cn, (1 << 10) + (r << 6))
#pragma unroll
        for (int r = 0; r < 16; ++r) GLDS(gsrc0 + (size_t)(479 - r) * Cn, (2 << 10) + (r << 6))
        WAIT16()

        a0 = (l == 48) ? 1.0f : 0.0f;   // beta[2l]
        a1 = (l == 47) ? 1.0f : 0.0f;   // beta[2l+1]

        // prime reg slots with steps k=0..3 (rows 0..3 of chunk 0)
        float pb0 = lds[(0 << 6) + 63], pl0 = lds[(0 << 6) + l];
        float pb1 = lds[(1 << 6) + 63], pl1 = lds[(1 << 6) + l];
        float pb2 = lds[(2 << 6) + 63], pl2 = lds[(2 << 6) + l];
        float pb3 = lds[(3 << 6) + 63], pl3 = lds[(3 << 6) + l];

#define BSTEP(PB, PL, LID, dopf)                                     \
    {                                                                \
        float nb_ = 0.0f, nl_ = 0.0f;                                \
        if (dopf) { nb_ = lds[(LID) + 63];                           \
                    nl_ = lds[(LID) + l]; }                          \
        float p0 = (PB) + EPSf;                                      \
        float p1 = lab_ok ? (PL) + EPSf : 0.0f;                      \
        float g0 = a0 * p0;                                          \
        float g1 = a1 * p1;                                          \
        float w_ = allow2 ? g1 : 0.0f;                               \
        float g0u = dpp_f0<0x130>(g0);                               \
        float wu  = dpp_f0<0x130>(w_);                               \
        int   Eh = dpp_i_keep<0x130>(E);                             \
        int   dm = max(E, Eh);                                       \
        int   kA = min(dm - E, 127);                                 \
        int   kH = min(dm - Eh, 127);                                \
        float sA = __int_as_float((127 - kA) << 23);                 \
        float sH = __int_as_float((127 - kH) << 23);                 \
        E = dm;                                                      \
        float up = g0u + wu;                                         \
        a0 = (g0 + g1) * sA;                                         \
        a1 = g1 * sA + up * sH;                                      \
        if (dopf) { (PB) = nb_; (PL) = nl_; }                        \
    }

#define B16(IB, INX)                                                 \
        BSTEP(pb0, pl0, (IB) + (4 << 6), true)                       \
        BSTEP(pb1, pl1, (IB) + (5 << 6), true)                       \
        BSTEP(pb2, pl2, (IB) + (6 << 6), true)                       \
        BSTEP(pb3, pl3, (IB) + (7 << 6), true)                       \
        RENORM()                                                     \
        BSTEP(pb0, pl0, (IB) + (8 << 6), true)                       \
        BSTEP(pb1, pl1, (IB) + (9 << 6), true)                       \
        BSTEP(pb2, pl2, (IB) + (10 << 6), true)                      \
        BSTEP(pb3, pl3, (IB) + (11 << 6), true)                      \
        RENORM()                                                     \
        BSTEP(pb0, pl0, (IB) + (12 << 6), true)                      \
        BSTEP(pb1, pl1, (IB) + (13 << 6), true)                      \
        BSTEP(pb2, pl2, (IB) + (14 << 6), true)                      \
        BSTEP(pb3, pl3, (IB) + (15 << 6), true)                      \
        RENORM()                                                     \
        BSTEP(pb0, pl0, (INX) + (0 << 6), true)                      \
        BSTEP(pb1, pl1, (INX) + (1 << 6), true)                      \
        BSTEP(pb2, pl2, (INX) + (2 << 6), true)                      \
        BSTEP(pb3, pl3, (INX) + (3 << 6), true)                      \
        RENORM()

        // chunk 0 (k=0..15)
        B16(0, (1 << 10))
        // boundary 0: issue chunk 3 (rows 463-r), wait16
#pragma unroll
        for (int r = 0; r < 16; ++r) GLDS(gsrc0 + (size_t)(463 - r) * Cn, (3 << 10) + (r << 6))
        WAIT16()

        // chunks 1..12
        for (int c = 1; c <= 12; ++c) {
            const int ib  = (c & 3) << 10;
            const int inx = ((c + 1) & 3) << 10;
            B16(ib, inx)
            const int top_ = 511 - (c + 3) * 16;   // first row of chunk c+3
            const float* gc_ = gsrc0 + (size_t)top_ * Cn;
            const int ibd_ = ((c + 3) & 3) << 10;
#pragma unroll
            for (int r = 0; r < 16; ++r) GLDS(gc_ - (size_t)r * Cn, ibd_ + (r << 6))
            WAIT16()
        }
        // chunk 13, drain, 14, 15
        B16((13 & 3) << 10, (14 & 3) << 10)
        WAIT0()
        B16((14 & 3) << 10, (15 & 3) << 10)
        {
            const int ib = (15 & 3) << 10;
            BSTEP(pb0, pl0, ib + (4 << 6), true)
            BSTEP(pb1, pl1, ib + (5 << 6), true)
            BSTEP(pb2, pl2, ib + (6 << 6), true)
            BSTEP(pb3, pl3, ib + (7 << 6), true)
            RENORM()
            BSTEP(pb0, pl0, ib + (8 << 6), true)
            BSTEP(pb1, pl1, ib + (9 << 6), true)
            BSTEP(pb2, pl2, ib + (10 << 6), true)
            BSTEP(pb3, pl3, ib + (11 << 6), true)
            RENORM()
            BSTEP(pb0, pl0, ib + (12 << 6), true)
            BSTEP(pb1, pl1, ib + (13 << 6), true)
            BSTEP(pb2, pl2, ib + (14 << 6), true)
            BSTEP(pb3, pl3, ib + (15 << 6), true)
            RENORM()
            BSTEP(pb0, pl0, 0, false)
            BSTEP(pb1, pl1, 0, false)
            BSTEP(pb2, pl2, 0, false)
            BSTEP(pb3, pl3, 0, false)
            RENORM()
        }
#undef BSTEP
#undef B16

        xb0[l] = a0; xb1[l] = a1; xEb[l] = E;
    }

    __syncthreads();

    if (w == 0) {
        // ===== combine: ll = sum_s alpha_255[s] * beta_255[s] =====
        float B0 = xb0[l], B1 = xb1[l];
        int   EB = xEb[l];
        float c  = a0 * B0 + a1 * B1;
        int   Ec = (c == 0.0f) ? (int)0xC0000000 : (E + EB);
        int m = Ec;
        m = max(m, dpp_i_keep<0x111>(m));
        m = max(m, dpp_i_keep<0x112>(m));
        m = max(m, dpp_i_keep<0x114>(m));
        m = max(m, dpp_i_keep<0x118>(m));
        if ((l & 15) == 15) rmax[l >> 4] = m;
        int Emax = max(max(rmax[0], rmax[1]), max(rmax[2], rmax[3]));
        int k_ = min(Emax - Ec, 127);
        float v = c * __int_as_float((127 - k_) << 23);
        v += dpp_f0<0x111>(v);
        v += dpp_f0<0x112>(v);
        v += dpp_f0<0x114>(v);
        v += dpp_f0<0x118>(v);
        if ((l & 15) == 15) rsum[l >> 4] = v;
        if (l == 0) {
            float sum = rsum[0] + rsum[1] + rsum[2] + rsum[3];
            out[b] = -LN2f * (__log2f(sum) + (float)Emax);
        }
    }
#undef GLDS
#undef WAIT16
#undef WAIT0
#undef RENORM
}

extern "C" void kernel_launch(void* const* d_in, const int* in_sizes, int n_in,
                              void* d_out, int out_size, void* d_ws, size_t ws_size,
                              hipStream_t stream) {
    const int*   yt  = (const int*)d_in[0];
    const float* yp  = (const float*)d_in[1];
    float*       out = (float*)d_out;
    hipLaunchKernelGGL(ctc_fwd, dim3(Bn), dim3(128), 0, stream, yt, yp, out);
}

// Round 13
// 27.674 us; speedup vs baseline: 1.2368x; 1.2368x over previous
//
#include <hip/hip_runtime.h>
#include <stdint.h>

#define Bn 512
#define Tn 512
#define Ln 48
#define Cn 128
#define BLANKC 127
#define EPSf 1e-7f
#define LN2f 0.6931471805599453f

// DPP with 0-fill for out-of-range source lanes (bound_ctrl=1)
template<int CTRL>
__device__ __forceinline__ float dpp_f0(float x) {
    int r = __builtin_amdgcn_update_dpp(0, __float_as_int(x), CTRL, 0xF, 0xF, true);
    return __int_as_float(r);
}
// DPP keep-self for out-of-range lanes (old=self, bound_ctrl=0)
template<int CTRL>
__device__ __forceinline__ int dpp_i_keep(int x) {
    return __builtin_amdgcn_update_dpp(x, x, CTRL, 0xF, 0xF, false);
}
// 0x138 wave_shr:1 ; 0x130 wave_shl:1 ; 0x111/2/4/8 row_shr:1/2/4/8

__global__ void __launch_bounds__(128, 1) ctc_fwd(
        const int* __restrict__ yt,
        const float* __restrict__ yp,
        float* __restrict__ out)
{
    const int b = blockIdx.x;
    const int w = threadIdx.x >> 6;   // 0 = forward wave, 1 = backward wave
    const int l = threadIdx.x & 63;

    // per-wave ring: 4 slots x 16 rows x 128 cols (full y_pred rows), 32 KB each
    __shared__ float ring[2][8192];
    __shared__ float xb0[64], xb1[64];
    __shared__ int   xEb[64];
    __shared__ int   rmax[4];
    __shared__ float rsum[4];

    const bool lab_ok = (l < Ln);
    int  cls1 = BLANKC;
    bool allow2 = false;
    if (lab_ok) {
        cls1 = yt[b * Ln + l];
        if (l >= 1) allow2 = (cls1 != yt[b * Ln + l - 1]);
    }

    float a0, a1;
    int   E = 0;
    float* lds = &ring[w][0];
    const float* gbase = yp + (size_t)b * (Tn * Cn);

    // cooperative full-row staging: 16 rows (8 KB) = 8 x global_load_lds dwordx4
#define STAGE(FIRSTROW, SLOTBASE)                                            \
    {                                                                        \
        const float* gr_ = gbase + (size_t)(FIRSTROW) * Cn + (l << 2);       \
        _Pragma("unroll")                                                    \
        for (int j = 0; j < 8; ++j)                                          \
            __builtin_amdgcn_global_load_lds(                                \
                (const __attribute__((address_space(1))) uint32_t*)(gr_ + j * 256), \
                (__attribute__((address_space(3))) uint32_t*)&lds[(SLOTBASE) + j * 256], \
                16, 0, 0);                                                   \
    }

#define WAIT8() asm volatile("s_waitcnt vmcnt(8)" ::: "memory");
#define WAIT0() asm volatile("s_waitcnt vmcnt(0)" ::: "memory");

#define RENORM()                                                     \
    {                                                                \
        float m_ = fmaxf(a0, a1);                                    \
        int   e_ = ((__float_as_int(m_) >> 23) & 0xFF) - 126;        \
        float sc_ = __int_as_float((127 - e_) << 23);                \
        a0 *= sc_; a1 *= sc_;                                        \
        E += e_;                                                     \
    }

    if (w == 0) {
        // ============ FORWARD: alpha_0 -> alpha_255 (255 steps) ===========
        STAGE(0, 0) STAGE(16, 2048) STAGE(32, 4096)
        WAIT8()   // chunks 0,1 resident

        a0 = (l == 0) ? lds[127]  + EPSf : 0.0f;   // row 0, blank col
        a1 = (l == 0) ? lds[cls1] + EPSf : 0.0f;   // row 0, label col (lane 0)

        // prime reg slots (slot = t&3) with rows 1..4
        float pb1 = lds[(1 << 7) + 127], pl1 = lds[(1 << 7) + cls1];
        float pb2 = lds[(2 << 7) + 127], pl2 = lds[(2 << 7) + cls1];
        float pb3 = lds[(3 << 7) + 127], pl3 = lds[(3 << 7) + cls1];
        float pb0 = lds[(4 << 7) + 127], pl0 = lds[(4 << 7) + cls1];

#define FSTEP(PB, PL, LID, dopf)                                     \
    {                                                                \
        float nb_ = 0.0f, nl_ = 0.0f;                                \
        if (dopf) { nb_ = lds[(LID) + 127];                          \
                    nl_ = lds[(LID) + cls1]; }                       \
        float p0 = (PB) + EPSf;                                      \
        float p1 = lab_ok ? (PL) + EPSf : 0.0f;                      \
        float h1 = dpp_f0<0x138>(a1);                                \
        int   Eh = dpp_i_keep<0x138>(E);                             \
        int   d_ = Eh - E;                                           \
        int   shA = min(-d_, 0);                                     \
        int   shH = min(d_, 0);                                      \
        E = max(E, Eh);                                              \
        float a0c = ldexpf(a0, shA);                                 \
        float a1c = ldexpf(a1, shA);                                 \
        float h1c = ldexpf(h1, shH);                                 \
        float t0 = a0c + h1c;                                        \
        float u  = a1c + (allow2 ? t0 : a0c);                        \
        a0 = t0 * p0;                                                \
        a1 = u * p1;                                                 \
        if (dopf) { (PB) = nb_; (PL) = nl_; }                        \
    }

        // ---- chunk 0: t = 1..15 (15 steps) ----
        FSTEP(pb1, pl1, (5 << 7), true)            // t=1
        FSTEP(pb2, pl2, (6 << 7), true)            // t=2
        FSTEP(pb3, pl3, (7 << 7), true)            // t=3
        RENORM()
        FSTEP(pb0, pl0, (8 << 7), true)            // t=4
        FSTEP(pb1, pl1, (9 << 7), true)            // t=5
        FSTEP(pb2, pl2, (10 << 7), true)           // t=6
        FSTEP(pb3, pl3, (11 << 7), true)           // t=7
        RENORM()
        FSTEP(pb0, pl0, (12 << 7), true)           // t=8
        FSTEP(pb1, pl1, (13 << 7), true)           // t=9
        FSTEP(pb2, pl2, (14 << 7), true)           // t=10
        FSTEP(pb3, pl3, (15 << 7), true)           // t=11
        RENORM()
        FSTEP(pb0, pl0, 2048 + (0 << 7), true)     // t=12
        FSTEP(pb1, pl1, 2048 + (1 << 7), true)     // t=13
        FSTEP(pb2, pl2, 2048 + (2 << 7), true)     // t=14
        FSTEP(pb3, pl3, 2048 + (3 << 7), true)     // t=15
        RENORM()
        STAGE(48, 6144) WAIT8()                    // boundary 0: chunk 3

#define F16(IB, INX)                                                 \
        FSTEP(pb0, pl0, (IB) + (4 << 7), true)                       \
        FSTEP(pb1, pl1, (IB) + (5 << 7), true)                       \
        FSTEP(pb2, pl2, (IB) + (6 << 7), true)                       \
        FSTEP(pb3, pl3, (IB) + (7 << 7), true)                       \
        RENORM()                                                     \
        FSTEP(pb0, pl0, (IB) + (8 << 7), true)                       \
        FSTEP(pb1, pl1, (IB) + (9 << 7), true)                       \
        FSTEP(pb2, pl2, (IB) + (10 << 7), true)                      \
        FSTEP(pb3, pl3, (IB) + (11 << 7), true)                      \
        RENORM()                                                     \
        FSTEP(pb0, pl0, (IB) + (12 << 7), true)                      \
        FSTEP(pb1, pl1, (IB) + (13 << 7), true)                      \
        FSTEP(pb2, pl2, (IB) + (14 << 7), true)                      \
        FSTEP(pb3, pl3, (IB) + (15 << 7), true)                      \
        RENORM()                                                     \
        FSTEP(pb0, pl0, (INX) + (0 << 7), true)                      \
        FSTEP(pb1, pl1, (INX) + (1 << 7), true)                      \
        FSTEP(pb2, pl2, (INX) + (2 << 7), true)                      \
        FSTEP(pb3, pl3, (INX) + (3 << 7), true)                      \
        RENORM()

        // chunks 1..12: consume, stage chunk c+3, counted wait
        for (int c = 1; c <= 12; ++c) {
            const int ib  = (c & 3) << 11;
            const int inx = ((c + 1) & 3) << 11;
            F16(ib, inx)
            STAGE((c + 3) * 16, ((c + 3) & 3) << 11)
            WAIT8()
        }
        // chunk 13, then drain remaining DMA (chunk 15 in flight)
        F16(1 << 11, 2 << 11)
        WAIT0()
        // chunk 14
        F16(2 << 11, 3 << 11)
        // chunk 15: t = 240..255; last 4 steps no prefetch
        {
            const int ib = 3 << 11;
            FSTEP(pb0, pl0, ib + (4 << 7), true)
            FSTEP(pb1, pl1, ib + (5 << 7), true)
            FSTEP(pb2, pl2, ib + (6 << 7), true)
            FSTEP(pb3, pl3, ib + (7 << 7), true)
            RENORM()
            FSTEP(pb0, pl0, ib + (8 << 7), true)
            FSTEP(pb1, pl1, ib + (9 << 7), true)
            FSTEP(pb2, pl2, ib + (10 << 7), true)
            FSTEP(pb3, pl3, ib + (11 << 7), true)
            RENORM()
            FSTEP(pb0, pl0, ib + (12 << 7), true)
            FSTEP(pb1, pl1, ib + (13 << 7), true)
            FSTEP(pb2, pl2, ib + (14 << 7), true)
            FSTEP(pb3, pl3, ib + (15 << 7), true)
            RENORM()
            FSTEP(pb0, pl0, 0, false)
            FSTEP(pb1, pl1, 0, false)
            FSTEP(pb2, pl2, 0, false)
            FSTEP(pb3, pl3, 0, false)
            RENORM()
        }
#undef FSTEP
#undef F16
    } else {
        // ============ BACKWARD: beta_511 -> beta_255 (256 steps) ==========
        // chunk c stages global rows (496-16c)..(511-16c) ascending;
        // step k of chunk c consumes global row 511-16c-k = LDS row 15-k
        STAGE(496, 0) STAGE(480, 2048) STAGE(464, 4096)
        WAIT8()

        a0 = (l == 48) ? 1.0f : 0.0f;   // beta[2l]
        a1 = (l == 47) ? 1.0f : 0.0f;   // beta[2l+1]

        // prime slots with steps k=0..3 of chunk 0 = rows 15..12
        float pb0 = lds[(15 << 7) + 127], pl0 = lds[(15 << 7) + cls1];
        float pb1 = lds[(14 << 7) + 127], pl1 = lds[(14 << 7) + cls1];
        float pb2 = lds[(13 << 7) + 127], pl2 = lds[(13 << 7) + cls1];
        float pb3 = lds[(12 << 7) + 127], pl3 = lds[(12 << 7) + cls1];

#define BSTEP(PB, PL, LID, dopf)                                     \
    {                                                                \
        float nb_ = 0.0f, nl_ = 0.0f;                                \
        if (dopf) { nb_ = lds[(LID) + 127];                          \
                    nl_ = lds[(LID) + cls1]; }                       \
        float p0 = (PB) + EPSf;                                      \
        float p1 = lab_ok ? (PL) + EPSf : 0.0f;                      \
        float g0 = a0 * p0;                                          \
        float g1 = a1 * p1;                                          \
        float w_ = allow2 ? g1 : 0.0f;                               \
        float g0u = dpp_f0<0x130>(g0);                               \
        float wu  = dpp_f0<0x130>(w_);                               \
        int   Eh = dpp_i_keep<0x130>(E);                             \
        int   d_ = Eh - E;                                           \
        int   shA = min(-d_, 0);                                     \
        int   shH = min(d_, 0);                                      \
        E = max(E, Eh);                                              \
        float up = g0u + wu;                                         \
        a0 = ldexpf(g0 + g1, shA);                                   \
        a1 = ldexpf(g1, shA) + ldexpf(up, shH);                      \
        if (dopf) { (PB) = nb_; (PL) = nl_; }                        \
    }

        // prefetch map: k<=11 -> same slot row 11-k ; k=12..15 -> next slot rows 15..12
#define B16(IB, INX)                                                 \
        BSTEP(pb0, pl0, (IB) + (11 << 7), true)                      \
        BSTEP(pb1, pl1, (IB) + (10 << 7), true)                      \
        BSTEP(pb2, pl2, (IB) + (9 << 7), true)                       \
        BSTEP(pb3, pl3, (IB) + (8 << 7), true)                       \
        RENORM()                                                     \
        BSTEP(pb0, pl0, (IB) + (7 << 7), true)                       \
        BSTEP(pb1, pl1, (IB) + (6 << 7), true)                       \
        BSTEP(pb2, pl2, (IB) + (5 << 7), true)                       \
        BSTEP(pb3, pl3, (IB) + (4 << 7), true)                       \
        RENORM()                                                     \
        BSTEP(pb0, pl0, (IB) + (3 << 7), true)                       \
        BSTEP(pb1, pl1, (IB) + (2 << 7), true)                       \
        BSTEP(pb2, pl2, (IB) + (1 << 7), true)                       \
        BSTEP(pb3, pl3, (IB) + (0 << 7), true)                       \
        RENORM()                                                     \
        BSTEP(pb0, pl0, (INX) + (15 << 7), true)                     \
        BSTEP(pb1, pl1, (INX) + (14 << 7), true)                     \
        BSTEP(pb2, pl2, (INX) + (13 << 7), true)                     \
        BSTEP(pb3, pl3, (INX) + (12 << 7), true)                     \
        RENORM()

        // chunk 0
        B16(0, 1 << 11)
        STAGE(448, 6144) WAIT8()   // boundary 0: chunk 3 = rows 448..463

        // chunks 1..12
        for (int c = 1; c <= 12; ++c) {
            const int ib  = (c & 3) << 11;
            const int inx = ((c + 1) & 3) << 11;
            B16(ib, inx)
            STAGE(496 - 16 * (c + 3), ((c + 3) & 3) << 11)
            WAIT8()
        }
        // chunk 13, drain, 14, 15
        B16(1 << 11, 2 << 11)
        WAIT0()
        B16(2 << 11, 3 << 11)
        {
            const int ib = 3 << 11;
            BSTEP(pb0, pl0, ib + (11 << 7), true)
            BSTEP(pb1, pl1, ib + (10 << 7), true)
            BSTEP(pb2, pl2, ib + (9 << 7), true)
            BSTEP(pb3, pl3, ib + (8 << 7), true)
            RENORM()
            BSTEP(pb0, pl0, ib + (7 << 7), true)
            BSTEP(pb1, pl1, ib + (6 << 7), true)
            BSTEP(pb2, pl2, ib + (5 << 7), true)
            BSTEP(pb3, pl3, ib + (4 << 7), true)
            RENORM()
            BSTEP(pb0, pl0, ib + (3 << 7), true)
            BSTEP(pb1, pl1, ib + (2 << 7), true)
            BSTEP(pb2, pl2, ib + (1 << 7), true)
            BSTEP(pb3, pl3, ib + (0 << 7), true)
            RENORM()
            BSTEP(pb0, pl0, 0, false)
            BSTEP(pb1, pl1, 0, false)
            BSTEP(pb2, pl2, 0, false)
            BSTEP(pb3, pl3, 0, false)
            RENORM()
        }
#undef BSTEP
#undef B16

        xb0[l] = a0; xb1[l] = a1; xEb[l] = E;
    }

    __syncthreads();

    if (w == 0) {
        // ===== combine: ll = sum_s alpha_255[s] * beta_255[s] (R9-validated) =====
        float B0 = xb0[l], B1 = xb1[l];
        int   EB = xEb[l];
        float c  = a0 * B0 + a1 * B1;
        int   Ec = (c == 0.0f) ? (int)0xC0000000 : (E + EB);
        int m = Ec;
        m = max(m, dpp_i_keep<0x111>(m));
        m = max(m, dpp_i_keep<0x112>(m));
        m = max(m, dpp_i_keep<0x114>(m));
        m = max(m, dpp_i_keep<0x118>(m));
        if ((l & 15) == 15) rmax[l >> 4] = m;
        int Emax = max(max(rmax[0], rmax[1]), max(rmax[2], rmax[3]));
        float v = ldexpf(c, Ec - Emax);
        v += dpp_f0<0x111>(v);
        v += dpp_f0<0x112>(v);
        v += dpp_f0<0x114>(v);
        v += dpp_f0<0x118>(v);
        if ((l & 15) == 15) rsum[l >> 4] = v;
        if (l == 0) {
            float sum = rsum[0] + rsum[1] + rsum[2] + rsum[3];
            out[b] = -LN2f * (__log2f(sum) + (float)Emax);
        }
    }
#undef STAGE
#undef WAIT8
#undef WAIT0
#undef RENORM
}

extern "C" void kernel_launch(void* const* d_in, const int* in_sizes, int n_in,
                              void* d_out, int out_size, void* d_ws, size_t ws_size,
                              hipStream_t stream) {
    const int*   yt  = (const int*)d_in[0];
    const float* yp  = (const float*)d_in[1];
    float*       out = (float*)d_out;
    hipLaunchKernelGGL(ctc_fwd, dim3(Bn), dim3(128), 0, stream, yt, yp, out);
}

// Round 14
// 26.793 us; speedup vs baseline: 1.2775x; 1.0329x over previous
//
#include <hip/hip_runtime.h>
#include <stdint.h>

#define Bn 512
#define Tn 512
#define Ln 48
#define Cn 128
#define BLANKC 127
#define EPSd 1e-7
#define LN2f 0.6931471805599453f

// f32 DPP, 0-fill OOB (bound_ctrl=1)
template<int CTRL>
__device__ __forceinline__ float dpp_f0(float x) {
    int r = __builtin_amdgcn_update_dpp(0, __float_as_int(x), CTRL, 0xF, 0xF, true);
    return __int_as_float(r);
}
// int DPP, keep-self OOB (identity for max-reduce)
template<int CTRL>
__device__ __forceinline__ int dpp_i_keep(int x) {
    return __builtin_amdgcn_update_dpp(x, x, CTRL, 0xF, 0xF, false);
}
// f64 DPP, 0-fill OOB: move both 32-bit halves identically (pure lane permute)
template<int CTRL>
__device__ __forceinline__ double dpp64_f0(double x) {
    long long v = __double_as_longlong(x);
    int lo = (int)(v & 0xffffffffLL);
    int hi = (int)(v >> 32);
    lo = __builtin_amdgcn_update_dpp(0, lo, CTRL, 0xF, 0xF, true);
    hi = __builtin_amdgcn_update_dpp(0, hi, CTRL, 0xF, 0xF, true);
    return __longlong_as_double(((long long)(unsigned int)lo) | ((long long)hi << 32));
}
// 0x138 wave_shr:1 ; 0x130 wave_shl:1 ; 0x111/2/4/8 row_shr:1/2/4/8

__global__ void __launch_bounds__(128, 1) ctc_fwd(
        const int* __restrict__ yt,
        const float* __restrict__ yp,
        float* __restrict__ out)
{
    const int b = blockIdx.x;
    const int w = threadIdx.x >> 6;   // 0 = forward wave, 1 = backward wave
    const int l = threadIdx.x & 63;

    __shared__ float  ring[2][8192];  // per-wave ring: 4 slots x 16 rows x 128 cols
    __shared__ double xb0d[64], xb1d[64];
    __shared__ int    xEbs;
    __shared__ int    rnmax[2][4];
    __shared__ double rsumd[4];

    const bool lab_ok = (l < Ln);
    int  cls1 = BLANKC;
    bool allow2 = false;
    if (lab_ok) {
        cls1 = yt[b * Ln + l];
        if (l >= 1) allow2 = (cls1 != yt[b * Ln + l - 1]);
    }

    double a0, a1;           // f64 linear alphas/betas, wave-uniform scale 2^E
    int    E = 0;
    float* lds = &ring[w][0];
    const float* gbase = yp + (size_t)b * (Tn * Cn);

#define STAGE(FIRSTROW, SLOTBASE)                                            \
    {                                                                        \
        const float* gr_ = gbase + (size_t)(FIRSTROW) * Cn + (l << 2);       \
        _Pragma("unroll")                                                    \
        for (int j = 0; j < 8; ++j)                                          \
            __builtin_amdgcn_global_load_lds(                                \
                (const __attribute__((address_space(1))) uint32_t*)(gr_ + j * 256), \
                (__attribute__((address_space(3))) uint32_t*)&lds[(SLOTBASE) + j * 256], \
                16, 0, 0);                                                   \
    }

#define WAIT8() asm volatile("s_waitcnt vmcnt(8)" ::: "memory");
#define WAIT0() asm volatile("s_waitcnt vmcnt(0)" ::: "memory");

    // wave-uniform renorm, once per 16-step chunk: wave-max of f64 hi-words ->
    // exact 2^-e rescale; E accumulates (uniform after broadcast via LDS).
#define RENORM64()                                                   \
    {                                                                \
        int h0_ = (int)(__double_as_longlong(a0) >> 32);             \
        int h1_ = (int)(__double_as_longlong(a1) >> 32);             \
        int mh_ = max(h0_, h1_);                                     \
        mh_ = max(mh_, dpp_i_keep<0x111>(mh_));                      \
        mh_ = max(mh_, dpp_i_keep<0x112>(mh_));                      \
        mh_ = max(mh_, dpp_i_keep<0x114>(mh_));                      \
        mh_ = max(mh_, dpp_i_keep<0x118>(mh_));                      \
        if ((l & 15) == 15) rnmax[w][l >> 4] = mh_;                  \
        int g_ = max(max(rnmax[w][0], rnmax[w][1]),                  \
                     max(rnmax[w][2], rnmax[w][3]));                 \
        int e_ = ((g_ >> 20) & 0x7FF) - 1022;                        \
        double sc_ = __longlong_as_double((long long)(1023 - e_) << 52); \
        a0 *= sc_; a1 *= sc_;                                        \
        E += e_;                                                     \
    }

    if (w == 0) {
        // ============ FORWARD: alpha_0 -> alpha_255 (255 steps) ===========
        STAGE(0, 0) STAGE(16, 2048) STAGE(32, 4096)
        WAIT8()   // chunks 0,1 resident

        a0 = (l == 0) ? (double)lds[127]  + EPSd : 0.0;
        a1 = (l == 0) ? (double)lds[cls1] + EPSd : 0.0;

        float pb1 = lds[(1 << 7) + 127], pl1 = lds[(1 << 7) + cls1];
        float pb2 = lds[(2 << 7) + 127], pl2 = lds[(2 << 7) + cls1];
        float pb3 = lds[(3 << 7) + 127], pl3 = lds[(3 << 7) + cls1];
        float pb0 = lds[(4 << 7) + 127], pl0 = lds[(4 << 7) + cls1];

#define FSTEP(PB, PL, LID, dopf)                                     \
    {                                                                \
        float nb_ = 0.0f, nl_ = 0.0f;                                \
        if (dopf) { nb_ = lds[(LID) + 127];                          \
                    nl_ = lds[(LID) + cls1]; }                       \
        double p0 = (double)(PB) + EPSd;                             \
        double p1 = lab_ok ? (double)(PL) + EPSd : 0.0;              \
        double h1 = dpp64_f0<0x138>(a1);                             \
        double t0 = a0 + h1;                                         \
        double u  = a1 + (allow2 ? t0 : a0);                         \
        a0 = t0 * p0;                                                \
        a1 = u * p1;                                                 \
        if (dopf) { (PB) = nb_; (PL) = nl_; }                        \
    }

        // ---- chunk 0: t = 1..15 ----
        FSTEP(pb1, pl1, (5 << 7), true)
        FSTEP(pb2, pl2, (6 << 7), true)
        FSTEP(pb3, pl3, (7 << 7), true)
        FSTEP(pb0, pl0, (8 << 7), true)
        FSTEP(pb1, pl1, (9 << 7), true)
        FSTEP(pb2, pl2, (10 << 7), true)
        FSTEP(pb3, pl3, (11 << 7), true)
        FSTEP(pb0, pl0, (12 << 7), true)
        FSTEP(pb1, pl1, (13 << 7), true)
        FSTEP(pb2, pl2, (14 << 7), true)
        FSTEP(pb3, pl3, (15 << 7), true)
        FSTEP(pb0, pl0, 2048 + (0 << 7), true)
        FSTEP(pb1, pl1, 2048 + (1 << 7), true)
        FSTEP(pb2, pl2, 2048 + (2 << 7), true)
        FSTEP(pb3, pl3, 2048 + (3 << 7), true)
        RENORM64()
        STAGE(48, 6144) WAIT8()

#define F16(IB, INX)                                                 \
        FSTEP(pb0, pl0, (IB) + (4 << 7), true)                       \
        FSTEP(pb1, pl1, (IB) + (5 << 7), true)                       \
        FSTEP(pb2, pl2, (IB) + (6 << 7), true)                       \
        FSTEP(pb3, pl3, (IB) + (7 << 7), true)                       \
        FSTEP(pb0, pl0, (IB) + (8 << 7), true)                       \
        FSTEP(pb1, pl1, (IB) + (9 << 7), true)                       \
        FSTEP(pb2, pl2, (IB) + (10 << 7), true)                      \
        FSTEP(pb3, pl3, (IB) + (11 << 7), true)                      \
        FSTEP(pb0, pl0, (IB) + (12 << 7), true)                      \
        FSTEP(pb1, pl1, (IB) + (13 << 7), true)                      \
        FSTEP(pb2, pl2, (IB) + (14 << 7), true)                      \
        FSTEP(pb3, pl3, (IB) + (15 << 7), true)                      \
        FSTEP(pb0, pl0, (INX) + (0 << 7), true)                      \
        FSTEP(pb1, pl1, (INX) + (1 << 7), true)                      \
        FSTEP(pb2, pl2, (INX) + (2 << 7), true)                      \
        FSTEP(pb3, pl3, (INX) + (3 << 7), true)                      \
        RENORM64()

        for (int c = 1; c <= 12; ++c) {
            const int ib  = (c & 3) << 11;
            const int inx = ((c + 1) & 3) << 11;
            F16(ib, inx)
            STAGE((c + 3) * 16, ((c + 3) & 3) << 11)
            WAIT8()
        }
        F16(1 << 11, 2 << 11)       // chunk 13
        WAIT0()
        F16(2 << 11, 3 << 11)       // chunk 14
        {                            // chunk 15: t = 240..255
            const int ib = 3 << 11;
            FSTEP(pb0, pl0, ib + (4 << 7), true)
            FSTEP(pb1, pl1, ib + (5 << 7), true)
            FSTEP(pb2, pl2, ib + (6 << 7), true)
            FSTEP(pb3, pl3, ib + (7 << 7), true)
            FSTEP(pb0, pl0, ib + (8 << 7), true)
            FSTEP(pb1, pl1, ib + (9 << 7), true)
            FSTEP(pb2, pl2, ib + (10 << 7), true)
            FSTEP(pb3, pl3, ib + (11 << 7), true)
            FSTEP(pb0, pl0, ib + (12 << 7), true)
            FSTEP(pb1, pl1, ib + (13 << 7), true)
            FSTEP(pb2, pl2, ib + (14 << 7), true)
            FSTEP(pb3, pl3, ib + (15 << 7), true)
            FSTEP(pb0, pl0, 0, false)
            FSTEP(pb1, pl1, 0, false)
            FSTEP(pb2, pl2, 0, false)
            FSTEP(pb3, pl3, 0, false)
            RENORM64()
        }
#undef FSTEP
#undef F16
    } else {
        // ============ BACKWARD: beta_511 -> beta_255 (256 steps) ==========
        STAGE(496, 0) STAGE(480, 2048) STAGE(464, 4096)
        WAIT8()

        a0 = (l == 48) ? 1.0 : 0.0;   // beta[2l]
        a1 = (l == 47) ? 1.0 : 0.0;   // beta[2l+1]

        // steps k=0..3 of chunk 0 = LDS rows 15..12
        float pb0 = lds[(15 << 7) + 127], pl0 = lds[(15 << 7) + cls1];
        float pb1 = lds[(14 << 7) + 127], pl1 = lds[(14 << 7) + cls1];
        float pb2 = lds[(13 << 7) + 127], pl2 = lds[(13 << 7) + cls1];
        float pb3 = lds[(12 << 7) + 127], pl3 = lds[(12 << 7) + cls1];

        // up(l) = [g0 + allow2*g1](l+1) — allow2 at source lane; ONE dpp64
#define BSTEP(PB, PL, LID, dopf)                                     \
    {                                                                \
        float nb_ = 0.0f, nl_ = 0.0f;                                \
        if (dopf) { nb_ = lds[(LID) + 127];                          \
                    nl_ = lds[(LID) + cls1]; }                       \
        double p0 = (double)(PB) + EPSd;                             \
        double p1 = lab_ok ? (double)(PL) + EPSd : 0.0;              \
        double g0 = a0 * p0;                                         \
        double g1 = a1 * p1;                                         \
        double pre = g0 + (allow2 ? g1 : 0.0);                       \
        double up = dpp64_f0<0x130>(pre);                            \
        a0 = g0 + g1;                                                \
        a1 = g1 + up;                                                \
        if (dopf) { (PB) = nb_; (PL) = nl_; }                        \
    }

#define B16(IB, INX)                                                 \
        BSTEP(pb0, pl0, (IB) + (11 << 7), true)                      \
        BSTEP(pb1, pl1, (IB) + (10 << 7), true)                      \
        BSTEP(pb2, pl2, (IB) + (9 << 7), true)                       \
        BSTEP(pb3, pl3, (IB) + (8 << 7), true)                       \
        BSTEP(pb0, pl0, (IB) + (7 << 7), true)                       \
        BSTEP(pb1, pl1, (IB) + (6 << 7), true)                       \
        BSTEP(pb2, pl2, (IB) + (5 << 7), true)                       \
        BSTEP(pb3, pl3, (IB) + (4 << 7), true)                       \
        BSTEP(pb0, pl0, (IB) + (3 << 7), true)                       \
        BSTEP(pb1, pl1, (IB) + (2 << 7), true)                       \
        BSTEP(pb2, pl2, (IB) + (1 << 7), true)                       \
        BSTEP(pb3, pl3, (IB) + (0 << 7), true)                       \
        BSTEP(pb0, pl0, (INX) + (15 << 7), true)                     \
        BSTEP(pb1, pl1, (INX) + (14 << 7), true)                     \
        BSTEP(pb2, pl2, (INX) + (13 << 7), true)                     \
        BSTEP(pb3, pl3, (INX) + (12 << 7), true)                     \
        RENORM64()

        B16(0, 1 << 11)              // chunk 0
        STAGE(448, 6144) WAIT8()

        for (int c = 1; c <= 12; ++c) {
            const int ib  = (c & 3) << 11;
            const int inx = ((c + 1) & 3) << 11;
            B16(ib, inx)
            STAGE(496 - 16 * (c + 3), ((c + 3) & 3) << 11)
            WAIT8()
        }
        B16(1 << 11, 2 << 11)        // chunk 13
        WAIT0()
        B16(2 << 11, 3 << 11)        // chunk 14
        {                            // chunk 15
            const int ib = 3 << 11;
            BSTEP(pb0, pl0, ib + (11 << 7), true)
            BSTEP(pb1, pl1, ib + (10 << 7), true)
            BSTEP(pb2, pl2, ib + (9 << 7), true)
            BSTEP(pb3, pl3, ib + (8 << 7), true)
            BSTEP(pb0, pl0, ib + (7 << 7), true)
            BSTEP(pb1, pl1, ib + (6 << 7), true)
            BSTEP(pb2, pl2, ib + (5 << 7), true)
            BSTEP(pb3, pl3, ib + (4 << 7), true)
            BSTEP(pb0, pl0, ib + (3 << 7), true)
            BSTEP(pb1, pl1, ib + (2 << 7), true)
            BSTEP(pb2, pl2, ib + (1 << 7), true)
            BSTEP(pb3, pl3, ib + (0 << 7), true)
            BSTEP(pb0, pl0, 0, false)
            BSTEP(pb1, pl1, 0, false)
            BSTEP(pb2, pl2, 0, false)
            BSTEP(pb3, pl3, 0, false)
            RENORM64()
        }
#undef BSTEP
#undef B16

        xb0d[l] = a0; xb1d[l] = a1;
        if (l == 0) xEbs = E;
    }

    __syncthreads();

    if (w == 0) {
        // ===== combine: ll = log(sum_s alpha[s]*beta[s]) + (Ef+Eb)*log(2) =====
        double c = a0 * xb0d[l] + a1 * xb1d[l];   // lanes >=49 are 0 on both sides
        c += dpp64_f0<0x111>(c);
        c += dpp64_f0<0x112>(c);
        c += dpp64_f0<0x114>(c);
        c += dpp64_f0<0x118>(c);
        if ((l & 15) == 15) rsumd[l >> 4] = c;
        if (l == 0) {
            double s = rsumd[0] + rsumd[1] + rsumd[2] + rsumd[3];
            long long sb = __double_as_longlong(s);
            int se = (int)((sb >> 52) & 0x7FF) - 1022;
            double m = __longlong_as_double((sb & 0x800FFFFFFFFFFFFFLL) | (1022LL << 52));
            float lg = __log2f((float)m) + (float)(se + E + xEbs);
            out[b] = -LN2f * lg;
        }
    }
#undef STAGE
#undef WAIT8
#undef WAIT0
#undef RENORM64
}

extern "C" void kernel_launch(void* const* d_in, const int* in_sizes, int n_in,
                              void* d_out, int out_size, void* d_ws, size_t ws_size,
                              hipStream_t stream) {
    const int*   yt  = (const int*)d_in[0];
    const float* yp  = (const float*)d_in[1];
    float*       out = (float*)d_out;
    hipLaunchKernelGGL(ctc_fwd, dim3(Bn), dim3(128), 0, stream, yt, yp, out);
}

// Round 15
// 26.639 us; speedup vs baseline: 1.2849x; 1.0058x over previous
//
#include <hip/hip_runtime.h>
#include <stdint.h>

#define Bn 512
#define Tn 512
#define Ln 48
#define Cn 128
#define BLANKC 127
#define EPSf 1e-7f
#define LN2f 0.6931471805599453f

// f32 DPP, 0-fill OOB (bound_ctrl=1)
template<int CTRL>
__device__ __forceinline__ float dpp_f0(float x) {
    int r = __builtin_amdgcn_update_dpp(0, __float_as_int(x), CTRL, 0xF, 0xF, true);
    return __int_as_float(r);
}
// int DPP, keep-self OOB (identity for max-reduce)
template<int CTRL>
__device__ __forceinline__ int dpp_i_keep(int x) {
    return __builtin_amdgcn_update_dpp(x, x, CTRL, 0xF, 0xF, false);
}
// f64 DPP, 0-fill OOB: move both 32-bit halves identically (pure lane permute)
template<int CTRL>
__device__ __forceinline__ double dpp64_f0(double x) {
    long long v = __double_as_longlong(x);
    int lo = (int)(v & 0xffffffffLL);
    int hi = (int)(v >> 32);
    lo = __builtin_amdgcn_update_dpp(0, lo, CTRL, 0xF, 0xF, true);
    hi = __builtin_amdgcn_update_dpp(0, hi, CTRL, 0xF, 0xF, true);
    return __longlong_as_double(((long long)(unsigned int)lo) | ((long long)hi << 32));
}
// 0x138 wave_shr:1 ; 0x130 wave_shl:1 ; 0x111/2/4/8 row_shr:1/2/4/8

__global__ void __launch_bounds__(128, 1) ctc_fwd(
        const int* __restrict__ yt,
        const float* __restrict__ yp,
        float* __restrict__ out)
{
    const int b = blockIdx.x;
    const int w = threadIdx.x >> 6;   // 0 = forward wave, 1 = backward wave
    const int l = threadIdx.x & 63;

    __shared__ float  ring[2][8192];  // per-wave ring: 4 slots x 16 rows x 128 cols
    __shared__ double xb0d[64], xb1d[64];
    __shared__ int    xEbs;
    __shared__ int    rnmax[2][4];
    __shared__ double rsumd[4];

    const bool lab_ok = (l < Ln);
    int  cls1 = BLANKC;
    bool allow2 = false;
    if (lab_ok) {
        cls1 = yt[b * Ln + l];
        if (l >= 1) allow2 = (cls1 != yt[b * Ln + l - 1]);
    }
    const double mA = allow2 ? 1.0 : 0.0;   // skip-transition mask as multiplier

    double a0, a1;           // f64 linear alphas/betas, wave-uniform scale 2^E
    int    E = 0;
    float* lds = &ring[w][0];
    const float* gbase = yp + (size_t)b * (Tn * Cn);

#define STAGE(FIRSTROW, SLOTBASE)                                            \
    {                                                                        \
        const float* gr_ = gbase + (size_t)(FIRSTROW) * Cn + (l << 2);       \
        _Pragma("unroll")                                                    \
        for (int j = 0; j < 8; ++j)                                          \
            __builtin_amdgcn_global_load_lds(                                \
                (const __attribute__((address_space(1))) uint32_t*)(gr_ + j * 256), \
                (__attribute__((address_space(3))) uint32_t*)&lds[(SLOTBASE) + j * 256], \
                16, 0, 0);                                                   \
    }

#define WAIT8() asm volatile("s_waitcnt vmcnt(8)" ::: "memory");
#define WAIT0() asm volatile("s_waitcnt vmcnt(0)" ::: "memory");

#define RENORM64()                                                   \
    {                                                                \
        int h0_ = (int)(__double_as_longlong(a0) >> 32);             \
        int h1_ = (int)(__double_as_longlong(a1) >> 32);             \
        int mh_ = max(h0_, h1_);                                     \
        mh_ = max(mh_, dpp_i_keep<0x111>(mh_));                      \
        mh_ = max(mh_, dpp_i_keep<0x112>(mh_));                      \
        mh_ = max(mh_, dpp_i_keep<0x114>(mh_));                      \
        mh_ = max(mh_, dpp_i_keep<0x118>(mh_));                      \
        if ((l & 15) == 15) rnmax[w][l >> 4] = mh_;                  \
        int g_ = max(max(rnmax[w][0], rnmax[w][1]),                  \
                     max(rnmax[w][2], rnmax[w][3]));                 \
        int e_ = ((g_ >> 20) & 0x7FF) - 1022;                        \
        double sc_ = __longlong_as_double((long long)(1023 - e_) << 52); \
        a0 *= sc_; a1 *= sc_;                                        \
        E += e_;                                                     \
    }

    if (w == 0) {
        // ============ FORWARD: alpha_0 -> alpha_255 (255 steps) ===========
        STAGE(0, 0) STAGE(16, 2048) STAGE(32, 4096)
        WAIT8()

        a0 = (l == 0) ? (double)(lds[127]  + EPSf) : 0.0;
        a1 = (l == 0) ? (double)(lds[cls1] + EPSf) : 0.0;

        float pb1 = lds[(1 << 7) + 127], pl1 = lds[(1 << 7) + cls1];
        float pb2 = lds[(2 << 7) + 127], pl2 = lds[(2 << 7) + cls1];
        float pb3 = lds[(3 << 7) + 127], pl3 = lds[(3 << 7) + cls1];
        float pb0 = lds[(4 << 7) + 127], pl0 = lds[(4 << 7) + cls1];

        // min-chain step: dpp64 -> {t0 = a0+h1 ; u = fma(mA,h1,a0+a1)} -> mul
#define FSTEP(PB, PL, LID, dopf)                                     \
    {                                                                \
        float nb_ = 0.0f, nl_ = 0.0f;                                \
        if (dopf) { nb_ = lds[(LID) + 127];                          \
                    nl_ = lds[(LID) + cls1]; }                       \
        float f0_ = (PB) + EPSf;                                     \
        float f1_ = lab_ok ? (PL) + EPSf : 0.0f;                     \
        double p0 = (double)f0_;                                     \
        double p1 = (double)f1_;                                     \
        double h1 = dpp64_f0<0x138>(a1);                             \
        double s01 = a0 + a1;                                        \
        double t0 = a0 + h1;                                         \
        double u  = fma(mA, h1, s01);                                \
        a0 = t0 * p0;                                                \
        a1 = u * p1;                                                 \
        if (dopf) { (PB) = nb_; (PL) = nl_; }                        \
    }

        // ---- chunk 0: t = 1..15 ----
        FSTEP(pb1, pl1, (5 << 7), true)
        FSTEP(pb2, pl2, (6 << 7), true)
        FSTEP(pb3, pl3, (7 << 7), true)
        FSTEP(pb0, pl0, (8 << 7), true)
        FSTEP(pb1, pl1, (9 << 7), true)
        FSTEP(pb2, pl2, (10 << 7), true)
        FSTEP(pb3, pl3, (11 << 7), true)
        FSTEP(pb0, pl0, (12 << 7), true)
        FSTEP(pb1, pl1, (13 << 7), true)
        FSTEP(pb2, pl2, (14 << 7), true)
        FSTEP(pb3, pl3, (15 << 7), true)
        FSTEP(pb0, pl0, 2048 + (0 << 7), true)
        FSTEP(pb1, pl1, 2048 + (1 << 7), true)
        FSTEP(pb2, pl2, 2048 + (2 << 7), true)
        FSTEP(pb3, pl3, 2048 + (3 << 7), true)
        RENORM64()
        STAGE(48, 6144) WAIT8()

#define F16(IB, INX)                                                 \
        FSTEP(pb0, pl0, (IB) + (4 << 7), true)                       \
        FSTEP(pb1, pl1, (IB) + (5 << 7), true)                       \
        FSTEP(pb2, pl2, (IB) + (6 << 7), true)                       \
        FSTEP(pb3, pl3, (IB) + (7 << 7), true)                       \
        FSTEP(pb0, pl0, (IB) + (8 << 7), true)                       \
        FSTEP(pb1, pl1, (IB) + (9 << 7), true)                       \
        FSTEP(pb2, pl2, (IB) + (10 << 7), true)                      \
        FSTEP(pb3, pl3, (IB) + (11 << 7), true)                      \
        FSTEP(pb0, pl0, (IB) + (12 << 7), true)                      \
        FSTEP(pb1, pl1, (IB) + (13 << 7), true)                      \
        FSTEP(pb2, pl2, (IB) + (14 << 7), true)                      \
        FSTEP(pb3, pl3, (IB) + (15 << 7), true)                      \
        FSTEP(pb0, pl0, (INX) + (0 << 7), true)                      \
        FSTEP(pb1, pl1, (INX) + (1 << 7), true)                      \
        FSTEP(pb2, pl2, (INX) + (2 << 7), true)                      \
        FSTEP(pb3, pl3, (INX) + (3 << 7), true)                      \
        RENORM64()

        for (int c = 1; c <= 12; ++c) {
            const int ib  = (c & 3) << 11;
            const int inx = ((c + 1) & 3) << 11;
            F16(ib, inx)
            STAGE((c + 3) * 16, ((c + 3) & 3) << 11)
            WAIT8()
        }
        F16(1 << 11, 2 << 11)       // chunk 13
        WAIT0()
        F16(2 << 11, 3 << 11)       // chunk 14
        {                            // chunk 15: t = 240..255
            const int ib = 3 << 11;
            FSTEP(pb0, pl0, ib + (4 << 7), true)
            FSTEP(pb1, pl1, ib + (5 << 7), true)
            FSTEP(pb2, pl2, ib + (6 << 7), true)
            FSTEP(pb3, pl3, ib + (7 << 7), true)
            FSTEP(pb0, pl0, ib + (8 << 7), true)
            FSTEP(pb1, pl1, ib + (9 << 7), true)
            FSTEP(pb2, pl2, ib + (10 << 7), true)
            FSTEP(pb3, pl3, ib + (11 << 7), true)
            FSTEP(pb0, pl0, ib + (12 << 7), true)
            FSTEP(pb1, pl1, ib + (13 << 7), true)
            FSTEP(pb2, pl2, ib + (14 << 7), true)
            FSTEP(pb3, pl3, ib + (15 << 7), true)
            FSTEP(pb0, pl0, 0, false)
            FSTEP(pb1, pl1, 0, false)
            FSTEP(pb2, pl2, 0, false)
            FSTEP(pb3, pl3, 0, false)
            RENORM64()
        }
#undef FSTEP
#undef F16
    } else {
        // ============ BACKWARD: beta_511 -> beta_255 (256 steps) ==========
        STAGE(496, 0) STAGE(480, 2048) STAGE(464, 4096)
        WAIT8()

        a0 = (l == 48) ? 1.0 : 0.0;   // beta[2l]
        a1 = (l == 47) ? 1.0 : 0.0;   // beta[2l+1]

        float pb0 = lds[(15 << 7) + 127], pl0 = lds[(15 << 7) + cls1];
        float pb1 = lds[(14 << 7) + 127], pl1 = lds[(14 << 7) + cls1];
        float pb2 = lds[(13 << 7) + 127], pl2 = lds[(13 << 7) + cls1];
        float pb3 = lds[(12 << 7) + 127], pl3 = lds[(12 << 7) + cls1];

        // pre = fma(mA, g1, g0) ; one dpp64 ; chain: mul -> fma -> dpp -> add
#define BSTEP(PB, PL, LID, dopf)                                     \
    {                                                                \
        float nb_ = 0.0f, nl_ = 0.0f;                                \
        if (dopf) { nb_ = lds[(LID) + 127];                          \
                    nl_ = lds[(LID) + cls1]; }                       \
        float f0_ = (PB) + EPSf;                                     \
        float f1_ = lab_ok ? (PL) + EPSf : 0.0f;                     \
        double p0 = (double)f0_;                                     \
        double p1 = (double)f1_;                                     \
        double g0 = a0 * p0;                                         \
        double g1 = a1 * p1;                                         \
        double pre = fma(mA, g1, g0);                                \
        double up = dpp64_f0<0x130>(pre);                            \
        a0 = g0 + g1;                                                \
        a1 = g1 + up;                                                \
        if (dopf) { (PB) = nb_; (PL) = nl_; }                        \
    }

#define B16(IB, INX)                                                 \
        BSTEP(pb0, pl0, (IB) + (11 << 7), true)                      \
        BSTEP(pb1, pl1, (IB) + (10 << 7), true)                      \
        BSTEP(pb2, pl2, (IB) + (9 << 7), true)                       \
        BSTEP(pb3, pl3, (IB) + (8 << 7), true)                       \
        BSTEP(pb0, pl0, (IB) + (7 << 7), true)                       \
        BSTEP(pb1, pl1, (IB) + (6 << 7), true)                       \
        BSTEP(pb2, pl2, (IB) + (5 << 7), true)                       \
        BSTEP(pb3, pl3, (IB) + (4 << 7), true)                       \
        BSTEP(pb0, pl0, (IB) + (3 << 7), true)                       \
        BSTEP(pb1, pl1, (IB) + (2 << 7), true)                       \
        BSTEP(pb2, pl2, (IB) + (1 << 7), true)                       \
        BSTEP(pb3, pl3, (IB) + (0 << 7), true)                       \
        BSTEP(pb0, pl0, (INX) + (15 << 7), true)                     \
        BSTEP(pb1, pl1, (INX) + (14 << 7), true)                     \
        BSTEP(pb2, pl2, (INX) + (13 << 7), true)                     \
        BSTEP(pb3, pl3, (INX) + (12 << 7), true)                     \
        RENORM64()

        B16(0, 1 << 11)              // chunk 0
        STAGE(448, 6144) WAIT8()

        for (int c = 1; c <= 12; ++c) {
            const int ib  = (c & 3) << 11;
            const int inx = ((c + 1) & 3) << 11;
            B16(ib, inx)
            STAGE(496 - 16 * (c + 3), ((c + 3) & 3) << 11)
            WAIT8()
        }
        B16(1 << 11, 2 << 11)        // chunk 13
        WAIT0()
        B16(2 << 11, 3 << 11)        // chunk 14
        {                            // chunk 15
            const int ib = 3 << 11;
            BSTEP(pb0, pl0, ib + (11 << 7), true)
            BSTEP(pb1, pl1, ib + (10 << 7), true)
            BSTEP(pb2, pl2, ib + (9 << 7), true)
            BSTEP(pb3, pl3, ib + (8 << 7), true)
            BSTEP(pb0, pl0, ib + (7 << 7), true)
            BSTEP(pb1, pl1, ib + (6 << 7), true)
            BSTEP(pb2, pl2, ib + (5 << 7), true)
            BSTEP(pb3, pl3, ib + (4 << 7), true)
            BSTEP(pb0, pl0, ib + (3 << 7), true)
            BSTEP(pb1, pl1, ib + (2 << 7), true)
            BSTEP(pb2, pl2, ib + (1 << 7), true)
            BSTEP(pb3, pl3, ib + (0 << 7), true)
            BSTEP(pb0, pl0, 0, false)
            BSTEP(pb1, pl1, 0, false)
            BSTEP(pb2, pl2, 0, false)
            BSTEP(pb3, pl3, 0, false)
            RENORM64()
        }
#undef BSTEP
#undef B16

        xb0d[l] = a0; xb1d[l] = a1;
        if (l == 0) xEbs = E;
    }

    __syncthreads();

    if (w == 0) {
        double c = a0 * xb0d[l] + a1 * xb1d[l];
        c += dpp64_f0<0x111>(c);
        c += dpp64_f0<0x112>(c);
        c += dpp64_f0<0x114>(c);
        c += dpp64_f0<0x118>(c);
        if ((l & 15) == 15) rsumd[l >> 4] = c;
        if (l == 0) {
            double s = rsumd[0] + rsumd[1] + rsumd[2] + rsumd[3];
            long long sb = __double_as_longlong(s);
            int se = (int)((sb >> 52) & 0x7FF) - 1022;
            double m = __longlong_as_double((sb & 0x800FFFFFFFFFFFFFLL) | (1022LL << 52));
            float lg = __log2f((float)m) + (float)(se + E + xEbs);
            out[b] = -LN2f * lg;
        }
    }
#undef STAGE
#undef WAIT8
#undef WAIT0
#undef RENORM64
}

extern "C" void kernel_launch(void* const* d_in, const int* in_sizes, int n_in,
                              void* d_out, int out_size, void* d_ws, size_t ws_size,
                              hipStream_t stream) {
    const int*   yt  = (const int*)d_in[0];
    const float* yp  = (const float*)d_in[1];
    float*       out = (float*)d_out;
    hipLaunchKernelGGL(ctc_fwd, dim3(Bn), dim3(128), 0, stream, yt, yp, out);
}